// Round 1
// baseline (1064.524 us; speedup 1.0000x reference)
//
#include <hip/hip_runtime.h>

// ---------------- problem constants ----------------
#define NVARS 700
#define MC    5558      // constraint count
#define OUTC  6258      // out columns we compute (skip unused xi0 block of 700)
#define MAXIT 20
// constraint segment bases: V:0 (stride 200/dof), A:1400 (198), J:2786 (196), P:4158 (200)

// =====================================================================
// qinv kernel: build Qt[101][100], Qt[k][i] = Qd_inv[i][k] (top block of
// KKT inverse), all math in f64.  C = 3I + 2D1'D1 + 2D2'D2 + 2T^2 L'L.
// C = L' B L with B = D' W D + 2T^2 I (D = L^-1, banded bw 3).
// =====================================================================
__device__ __forceinline__ double Wfun(int a, int b) {
  if (a < 0 || a > 99 || b < 0 || b > 99) return 0.0;
  int d = a - b; if (d < 0) d = -d;
  int l = a < b ? a : b;
  const double iT2 = 2500.0;       // 1/T^2
  const double iT4 = 6250000.0;    // 1/T^4
  double w = 0.0;
  if (d == 0) {
    w = 3.0;
    w += 2.0 * iT2 * (double)((a <= 98 ? 1 : 0) + (a >= 1 ? 1 : 0));
    double dd = (double)(((a - 2) >= 0 && (a - 2) <= 97) ? 1 : 0)
              + 4.0 * (double)(((a - 1) >= 0 && (a - 1) <= 97) ? 1 : 0)
              + (double)((a <= 97) ? 1 : 0);
    w += 2.0 * iT4 * dd;
  } else if (d == 1) {
    w = -2.0 * iT2;
    double dd = -2.0 * (double)(((l - 1) >= 0 && (l - 1) <= 97) ? 1 : 0)
                - 2.0 * (double)((l <= 97) ? 1 : 0);
    w += 2.0 * iT4 * dd;
  } else if (d == 2) {
    w = 2.0 * iT4 * (double)((l <= 97) ? 1 : 0);
  }
  return w;
}

__global__ __launch_bounds__(128) void qinv_kernel(double* __restrict__ zbuf,  // 100*128 f64
                                                   double* __restrict__ cid,   // 100*100 f64 (C^-1)
                                                   float* __restrict__ Qt)     // 101*100 f32
{
  __shared__ double Bb[100][4];   // lower band of B, Bb[i][k] = B[i][i-k]
  __shared__ double Gb[100][4];   // Cholesky factor band
  __shared__ double invd[100];
  int tid = threadIdx.x;
  for (int q = tid; q < 400; q += 128) {
    int i = q >> 2, k = q & 3;
    int j = i - k;
    double v = 0.0;
    if (j >= 0) {
      v = Wfun(i, j) - Wfun(i + 1, j) - Wfun(i, j + 1) + Wfun(i + 1, j + 1);
      if (k == 0) v += 2.0 * 0.02 * 0.02;   // + 2 T^2 I
    }
    Bb[i][k] = v;
  }
  __syncthreads();
  if (tid == 0) {                 // banded Cholesky B = G G'
    for (int i = 0; i < 100; ++i) {
      for (int k = 3; k >= 1; --k) {
        int j = i - k;
        if (j < 0) { Gb[i][k] = 0.0; continue; }
        double s = Bb[i][k];
        for (int m = k + 1; m <= 3; ++m)
          if (m <= i) s -= Gb[i][m] * Gb[j][m - k];
        Gb[i][k] = s * invd[j];
      }
      double s = Bb[i][0];
      for (int m = 1; m <= 3; ++m)
        if (m <= i) s -= Gb[i][m] * Gb[i][m];
      double g = sqrt(s);
      Gb[i][0] = g;
      invd[i] = 1.0 / g;
    }
  }
  __syncthreads();
  if (tid < 100) {                // column c of C^-1 = D B^-1 D' e_c
    int c = tid;
    double z0 = 0, z1 = 0, z2 = 0;
    for (int i = 0; i < 100; ++i) {           // forward: G z = D' e_c
      double v = (i == c ? 1.0 : 0.0) - (i == (c - 1) ? 1.0 : 0.0);
      double s = v - Gb[i][1] * z0 - Gb[i][2] * z1 - Gb[i][3] * z2;
      double z = s * invd[i];
      zbuf[i * 128 + c] = z;
      z2 = z1; z1 = z0; z0 = z;
    }
    double y0 = 0, y1 = 0, y2 = 0;
    for (int i = 99; i >= 0; --i) {           // back: G' y = z
      double s = zbuf[i * 128 + c];
      if (i + 1 <= 99) s -= Gb[i + 1][1] * y0;
      if (i + 2 <= 99) s -= Gb[i + 2][2] * y1;
      if (i + 3 <= 99) s -= Gb[i + 3][3] * y2;
      double y = s * invd[i];
      zbuf[i * 128 + c] = y;
      y2 = y1; y1 = y0; y0 = y;
    }
    double ym = 0.0;
    for (int i = 0; i < 100; ++i) {           // x = D y (differences)
      double y = zbuf[i * 128 + c];
      cid[i * 100 + c] = y - ym;
      ym = y;
    }
  }
  __syncthreads();
  double invs = 1.0 / cid[0];                 // s = C^-1[0][0]
  for (int q = tid; q < 101 * 100; q += 128) {
    int k = q / 100, i = q - (q / 100) * 100;
    double val;
    if (k < 100) val = cid[i * 100 + k] - cid[i * 100] * cid[k] * invs;
    else         val = cid[i * 100] * invs;
    Qt[k * 100 + i] = (float)val;
  }
}

// =====================================================================
// per-column quantiles via bitonic sort (1024 rows per column)
// =====================================================================
__global__ __launch_bounds__(256) void quantile_kernel(const float* __restrict__ in,
                                                       float* __restrict__ med,
                                                       float* __restrict__ rinv)
{
  __shared__ float v[1024];
  int c = blockIdx.x, tid = threadIdx.x;
  for (int i = tid; i < 1024; i += 256) v[i] = in[i * NVARS + c];
  __syncthreads();
  for (int k = 2; k <= 1024; k <<= 1) {
    for (int j = k >> 1; j > 0; j >>= 1) {
      for (int i = tid; i < 1024; i += 256) {
        int ixj = i ^ j;
        if (ixj > i) {
          float a = v[i], b2 = v[ixj];
          bool up = ((i & k) == 0);
          if ((a > b2) == up) { v[i] = b2; v[ixj] = a; }
        }
      }
      __syncthreads();
    }
  }
  if (tid == 0) {
    float m  = v[511];                                    // method='lower', idx=floor(511.5)
    float q1 = v[255] + 0.75f * (v[256] - v[255]);        // 0.25*(n-1)=255.75
    float q3 = v[767] + 0.25f * (v[768] - v[767]);        // 0.75*(n-1)=767.25
    float iq = q3 - q1;
    if (iq == 0.f) iq = 1.f;
    med[c] = m;
    rinv[c] = 1.f / iq;
  }
}

__global__ __launch_bounds__(256) void normalize_kernel(const float* __restrict__ in,
                                                        const float* __restrict__ med,
                                                        const float* __restrict__ rinv,
                                                        float* __restrict__ An)
{
  int idx = blockIdx.x * 256 + threadIdx.x;
  if (idx < 1024 * NVARS) {
    int c = idx % NVARS;
    An[idx] = (in[idx] - med[c]) * rinv[c];
  }
}

// =====================================================================
// simple f32 tiled GEMM: C[M x N] = A[M x K] @ B[K x N] + bias (opt relu)
// BM=BN=64, BK=16, 256 threads, 4x4 micro-tile
// =====================================================================
template <bool RELU>
__global__ __launch_bounds__(256) void gemm_kernel(const float* __restrict__ A, int lda,
                                                   const float* __restrict__ B, int ldb,
                                                   const float* __restrict__ bias,
                                                   float* __restrict__ C, int ldc,
                                                   int N, int K)
{
  __shared__ __align__(16) float As[16][68];
  __shared__ __align__(16) float Bs[16][64];
  int tid = threadIdx.x;
  int bm = blockIdx.y * 64, bn = blockIdx.x * 64;
  int tx = tid & 15, ty = tid >> 4;
  float acc[4][4] = {};
  for (int k0 = 0; k0 < K; k0 += 16) {
    {
      int q = tid * 4;
      int m = q >> 4, kk = q & 15;
      const float* ap = A + (size_t)(bm + m) * lda + k0;
#pragma unroll
      for (int s2 = 0; s2 < 4; ++s2) {
        int kc = kk + s2;
        As[kc][m] = (k0 + kc < K) ? ap[kc] : 0.f;
      }
    }
#pragma unroll
    for (int s2 = 0; s2 < 4; ++s2) {
      int q = tid + s2 * 256;
      int kk = q >> 6, n = q & 63;
      float val = 0.f;
      if (k0 + kk < K && bn + n < N) val = B[(size_t)(k0 + kk) * ldb + bn + n];
      Bs[kk][n] = val;
    }
    __syncthreads();
#pragma unroll
    for (int kk = 0; kk < 16; ++kk) {
      float4 av = *reinterpret_cast<const float4*>(&As[kk][ty * 4]);
      float4 bv = *reinterpret_cast<const float4*>(&Bs[kk][tx * 4]);
      acc[0][0] += av.x * bv.x; acc[0][1] += av.x * bv.y; acc[0][2] += av.x * bv.z; acc[0][3] += av.x * bv.w;
      acc[1][0] += av.y * bv.x; acc[1][1] += av.y * bv.y; acc[1][2] += av.y * bv.z; acc[1][3] += av.y * bv.w;
      acc[2][0] += av.z * bv.x; acc[2][1] += av.z * bv.y; acc[2][2] += av.z * bv.z; acc[2][3] += av.z * bv.w;
      acc[3][0] += av.w * bv.x; acc[3][1] += av.w * bv.y; acc[3][2] += av.w * bv.z; acc[3][3] += av.w * bv.w;
    }
    __syncthreads();
  }
#pragma unroll
  for (int i = 0; i < 4; ++i) {
    int m = bm + ty * 4 + i;
#pragma unroll
    for (int j = 0; j < 4; ++j) {
      int n = bn + tx * 4 + j;
      if (n < N) {
        float r = acc[i][j] + bias[n];
        if (RELU) r = fmaxf(r, 0.f);
        C[(size_t)m * ldc + n] = r;
      }
    }
  }
}

// =====================================================================
// solver: one block per batch sample; 20 ADMM iterations fully in LDS.
// State: t[m] = b[m] - Ax[m]  (so s = relu(t), res = relu(-t)); lam[700].
// =====================================================================
__global__ __launch_bounds__(256) void solver_kernel(const float* __restrict__ out2,
                                                     const float* __restrict__ input,
                                                     const float* __restrict__ theta,
                                                     const float* __restrict__ vstart,
                                                     const float* __restrict__ Qt,
                                                     float* __restrict__ out)
{
  __shared__ float t[MC];
  __shared__ float lam[700], xs[700], ru[700], xi[700];
  __shared__ float sa[896], sb[896];
  __shared__ float red[12];
  __shared__ float vs[7];
  int b = blockIdx.x, tid = threadIdx.x;
  const float* orow = out2 + (size_t)b * OUTC;
  for (int q = tid; q < 700; q += 256) { lam[q] = orow[q]; xs[q] = input[b * NVARS + q]; }
  for (int m = tid; m < MC; m += 256) t[m] = fmaxf(orow[700 + m], 0.f);   // s0
  if (tid < 7) vs[tid] = vstart[b * 7 + tid];
  float th = theta[b];
  float ap = 0.f, af = 0.f;
  __syncthreads();

  for (int it = 0; it < MAXIT; ++it) {
    // ---- u = A^T (b - s): pos part needs reverse cumsum ----
    for (int q = tid; q < 896; q += 256) {
      int d = q >> 7, i = q & 127;
      float w = 0.f;
      if (i < 100) {
        int pp = 4158 + d * 200 + i;
        w = fmaxf(t[pp + 100], 0.f) - fmaxf(t[pp], 0.f);
        if (d == 3) w -= 2.f * th;         // pos b-values: rows<700 get -theta, >=700 get +theta
      }
      sa[q] = w;
    }
    __syncthreads();
    float* cur = sa; float* nxt = sb;
    for (int off = 1; off < 128; off <<= 1) {       // reverse inclusive scan
      for (int q = tid; q < 896; q += 256) {
        int i = q & 127;
        float vv = cur[q];
        if (i + off < 128) vv += cur[q + off];
        nxt[q] = vv;
      }
      __syncthreads();
      float* tm2 = cur; cur = nxt; nxt = tm2;
    }
    // ru = lam + xs + u   (= -lincost)
    for (int q = tid; q < 700; q += 256) {
      int d = q / 100, i = q - d * 100;
      int vp = d * 200 + i;
      float u = fmaxf(t[vp + 100], 0.f) - fmaxf(t[vp], 0.f);
      int ab = 1400 + d * 198;
      float ya = 0.f, yb = 0.f;
      if (i >= 1)  { int a2 = ab + i - 1; ya = fmaxf(t[a2 + 99], 0.f) - fmaxf(t[a2], 0.f); }
      if (i <= 98) { int a2 = ab + i;     yb = fmaxf(t[a2 + 99], 0.f) - fmaxf(t[a2], 0.f); }
      u += (ya - yb) * 50.f;
      int jb = 2786 + d * 196;
      float z2 = 0.f, z1 = 0.f, z0 = 0.f;
      if (i >= 2)            { int a2 = jb + i - 2; z2 = fmaxf(t[a2 + 98], 0.f) - fmaxf(t[a2], 0.f); }
      if (i >= 1 && i <= 98) { int a2 = jb + i - 1; z1 = fmaxf(t[a2 + 98], 0.f) - fmaxf(t[a2], 0.f); }
      if (i <= 97)           { int a2 = jb + i;     z0 = fmaxf(t[a2 + 98], 0.f) - fmaxf(t[a2], 0.f); }
      u += (z2 - 2.f * z1 + z0) * 2500.f;
      u += 0.02f * cur[(d << 7) + i];
      ru[q] = lam[q] + xs[q] + u;
    }
    __syncthreads();
    // ---- xi = Qd_inv_top @ [ru; v_start], per dof (shared Qt) ----
    if (tid < 100) {
      int i = tid;
      float a0 = 0, a1 = 0, a2 = 0, a3 = 0;
      for (int k = 0; k < 100; ++k) {
        float qv = Qt[k * 100 + i];
        a0 += qv * ru[k];       a1 += qv * ru[100 + k];
        a2 += qv * ru[200 + k]; a3 += qv * ru[300 + k];
      }
      float qv = Qt[10000 + i];
      a0 += qv * vs[0]; a1 += qv * vs[1]; a2 += qv * vs[2]; a3 += qv * vs[3];
      xi[i] = a0; xi[100 + i] = a1; xi[200 + i] = a2; xi[300 + i] = a3;
    } else if (tid >= 128 && tid < 228) {
      int i = tid - 128;
      float a0 = 0, a1 = 0, a2 = 0;
      for (int k = 0; k < 100; ++k) {
        float qv = Qt[k * 100 + i];
        a0 += qv * ru[400 + k]; a1 += qv * ru[500 + k]; a2 += qv * ru[600 + k];
      }
      float qv = Qt[10000 + i];
      a0 += qv * vs[4]; a1 += qv * vs[5]; a2 += qv * vs[6];
      xi[400 + i] = a0; xi[500 + i] = a1; xi[600 + i] = a2;
    }
    __syncthreads();
    // ---- forward cumsum of xi (for pos rows) ----
    for (int q = tid; q < 896; q += 256) {
      int d = q >> 7, i = q & 127;
      sa[q] = (i < 100) ? xi[d * 100 + i] : 0.f;
    }
    __syncthreads();
    cur = sa; nxt = sb;
    for (int off = 1; off < 128; off <<= 1) {
      for (int q = tid; q < 896; q += 256) {
        int i = q & 127;
        float vv = cur[q];
        if (i >= off) vv += cur[q - off];
        nxt[q] = vv;
      }
      __syncthreads();
      float* tm2 = cur; cur = nxt; nxt = tm2;
    }
    // ---- t update: t = b - Ax; norms of res and s-diff ----
    float r2 = 0.f, ds2 = 0.f;
    for (int m = tid; m < MC; m += 256) {
      float Ax, bc; int d, i, r; bool neg;
      if (m < 1400) {
        d = m / 200; r = m - d * 200; neg = (r >= 100); i = neg ? r - 100 : r;
        Ax = xi[d * 100 + i]; bc = 1.f;
      } else if (m < 2786) {
        int q2 = m - 1400; d = q2 / 198; r = q2 - d * 198; neg = (r >= 99); i = neg ? r - 99 : r;
        int x0 = d * 100 + i;
        Ax = (xi[x0 + 1] - xi[x0]) * 50.f; bc = 2.f;
      } else if (m < 4158) {
        int q2 = m - 2786; d = q2 / 196; r = q2 - d * 196; neg = (r >= 98); i = neg ? r - 98 : r;
        int x0 = d * 100 + i;
        Ax = (xi[x0 + 2] - 2.f * xi[x0 + 1] + xi[x0]) * 2500.f; bc = 5.f;
      } else {
        int q2 = m - 4158; d = q2 / 200; r = q2 - d * 200; neg = (r >= 100); i = neg ? r - 100 : r;
        Ax = 0.02f * cur[(d << 7) + i];
        bc = (q2 < 700) ? (3.14f - th) : (3.14f + th);
      }
      if (neg) Ax = -Ax;
      float tn = bc - Ax;
      float told = t[m];
      float dd = fmaxf(told, 0.f) - fmaxf(tn, 0.f);
      ds2 += dd * dd;
      float res = fmaxf(-tn, 0.f);
      r2 += res * res;
      t[m] = tn;
    }
#pragma unroll
    for (int o = 32; o > 0; o >>= 1) { r2 += __shfl_down(r2, o); ds2 += __shfl_down(ds2, o); }
    if ((tid & 63) == 0) { red[tid >> 6] = r2; red[4 + (tid >> 6)] = ds2; }
    __syncthreads();
    // ---- g = A^T res (res = relu(-t)); lam -= g ----
    for (int q = tid; q < 896; q += 256) {
      int d = q >> 7, i = q & 127;
      float w = 0.f;
      if (i < 100) {
        int pp = 4158 + d * 200 + i;
        w = fmaxf(-t[pp], 0.f) - fmaxf(-t[pp + 100], 0.f);
      }
      sa[q] = w;
    }
    __syncthreads();
    cur = sa; nxt = sb;
    for (int off = 1; off < 128; off <<= 1) {
      for (int q = tid; q < 896; q += 256) {
        int i = q & 127;
        float vv = cur[q];
        if (i + off < 128) vv += cur[q + off];
        nxt[q] = vv;
      }
      __syncthreads();
      float* tm2 = cur; cur = nxt; nxt = tm2;
    }
    float dl2 = 0.f;
    for (int q = tid; q < 700; q += 256) {
      int d = q / 100, i = q - d * 100;
      int vp = d * 200 + i;
      float g = fmaxf(-t[vp], 0.f) - fmaxf(-t[vp + 100], 0.f);
      int ab = 1400 + d * 198;
      float ya = 0.f, yb = 0.f;
      if (i >= 1)  { int a2 = ab + i - 1; ya = fmaxf(-t[a2], 0.f) - fmaxf(-t[a2 + 99], 0.f); }
      if (i <= 98) { int a2 = ab + i;     yb = fmaxf(-t[a2], 0.f) - fmaxf(-t[a2 + 99], 0.f); }
      g += (ya - yb) * 50.f;
      int jb = 2786 + d * 196;
      float z2 = 0.f, z1 = 0.f, z0 = 0.f;
      if (i >= 2)            { int a2 = jb + i - 2; z2 = fmaxf(-t[a2], 0.f) - fmaxf(-t[a2 + 98], 0.f); }
      if (i >= 1 && i <= 98) { int a2 = jb + i - 1; z1 = fmaxf(-t[a2], 0.f) - fmaxf(-t[a2 + 98], 0.f); }
      if (i <= 97)           { int a2 = jb + i;     z0 = fmaxf(-t[a2], 0.f) - fmaxf(-t[a2 + 98], 0.f); }
      g += (z2 - 2.f * z1 + z0) * 2500.f;
      g += 0.02f * cur[(d << 7) + i];
      lam[q] -= g;
      dl2 += g * g;
    }
#pragma unroll
    for (int o = 32; o > 0; o >>= 1) dl2 += __shfl_down(dl2, o);
    if ((tid & 63) == 0) red[8 + (tid >> 6)] = dl2;
    __syncthreads();
    if (tid == 0) {
      float R2  = red[0] + red[1] + red[2] + red[3];
      float DS2 = red[4] + red[5] + red[6] + red[7];
      float DL2 = red[8] + red[9] + red[10] + red[11];
      float pr = sqrtf(R2);
      float fp = sqrtf(DL2) + sqrtf(DS2);
      out[718848 + it * 1024 + b] = pr;   // primal_res[it, b]
      out[739328 + it * 1024 + b] = fp;   // fixed_res[it, b]
      ap += pr; af += fp;
    }
    __syncthreads();
  }
  for (int q = tid; q < 700; q += 256) out[(size_t)b * 700 + q] = xi[q];  // xi_f
  if (tid == 0) {
    out[716800 + b] = af / 20.f;   // avg_fixed
    out[717824 + b] = ap / 20.f;   // avg_primal
  }
}

// =====================================================================
extern "C" void kernel_launch(void* const* d_in, const int* in_sizes, int n_in,
                              void* d_out, int out_size, void* d_ws, size_t ws_size,
                              hipStream_t stream) {
  (void)in_sizes; (void)n_in; (void)out_size;
  const float* input  = (const float*)d_in[0];
  const float* theta  = (const float*)d_in[1];
  const float* vstart = (const float*)d_in[2];
  const float* W1     = (const float*)d_in[3];
  const float* b1     = (const float*)d_in[4];
  const float* W2     = (const float*)d_in[5];
  const float* b2     = (const float*)d_in[6];
  float* out = (float*)d_out;

  // ws layout (f64 region first, then f32 region)
  double* wsd  = (double*)d_ws;
  double* zbuf = wsd;              // 12800 doubles
  double* cid  = wsd + 12800;      // 10000 doubles  -> ends at byte 182400
  float* wsf  = (float*)d_ws;
  float* Qt   = wsf + 45600;       // 10100 floats
  float* med  = wsf + 55704;       // 700
  float* rinv = wsf + 56408;       // 700
  float* An   = wsf + 57112;       // 716800
  float* h    = wsf + 773912;      // 1048576
  float* out2 = wsf + 1822488;     // 6408192 -> total ~32.9 MB
  if (ws_size < (size_t)(1822488 + 6408192) * 4) return;  // defensive

  hipLaunchKernelGGL(qinv_kernel, dim3(1), dim3(128), 0, stream, zbuf, cid, Qt);
  hipLaunchKernelGGL(quantile_kernel, dim3(700), dim3(256), 0, stream, input, med, rinv);
  hipLaunchKernelGGL(normalize_kernel, dim3(2800), dim3(256), 0, stream, input, med, rinv, An);
  hipLaunchKernelGGL((gemm_kernel<true>), dim3(16, 16), dim3(256), 0, stream,
                     An, NVARS, W1, 1024, b1, h, 1024, 1024, NVARS);
  hipLaunchKernelGGL((gemm_kernel<false>), dim3(98, 16), dim3(256), 0, stream,
                     h, 1024, W2 + 700, 6958, b2 + 700, out2, OUTC, OUTC, 1024);
  hipLaunchKernelGGL(solver_kernel, dim3(1024), dim3(256), 0, stream,
                     out2, input, theta, vstart, Qt, out);
}

// Round 2
// 902.707 us; speedup vs baseline: 1.1793x; 1.1793x over previous
//
#include <hip/hip_runtime.h>

// ---------------- problem constants ----------------
#define NVARS 700
#define MC    5558
#define OUTC  6258
#define MAXIT 20

// =====================================================================
// qinv kernel (unchanged from R1): Qt[k*100+i], k in [0,101)
// =====================================================================
__device__ __forceinline__ double Wfun(int a, int b) {
  if (a < 0 || a > 99 || b < 0 || b > 99) return 0.0;
  int d = a - b; if (d < 0) d = -d;
  int l = a < b ? a : b;
  const double iT2 = 2500.0;
  const double iT4 = 6250000.0;
  double w = 0.0;
  if (d == 0) {
    w = 3.0;
    w += 2.0 * iT2 * (double)((a <= 98 ? 1 : 0) + (a >= 1 ? 1 : 0));
    double dd = (double)(((a - 2) >= 0 && (a - 2) <= 97) ? 1 : 0)
              + 4.0 * (double)(((a - 1) >= 0 && (a - 1) <= 97) ? 1 : 0)
              + (double)((a <= 97) ? 1 : 0);
    w += 2.0 * iT4 * dd;
  } else if (d == 1) {
    w = -2.0 * iT2;
    double dd = -2.0 * (double)(((l - 1) >= 0 && (l - 1) <= 97) ? 1 : 0)
                - 2.0 * (double)((l <= 97) ? 1 : 0);
    w += 2.0 * iT4 * dd;
  } else if (d == 2) {
    w = 2.0 * iT4 * (double)((l <= 97) ? 1 : 0);
  }
  return w;
}

__global__ __launch_bounds__(128) void qinv_kernel(double* __restrict__ zbuf,
                                                   double* __restrict__ cid,
                                                   float* __restrict__ Qt)
{
  __shared__ double Bb[100][4];
  __shared__ double Gb[100][4];
  __shared__ double invd[100];
  int tid = threadIdx.x;
  for (int q = tid; q < 400; q += 128) {
    int i = q >> 2, k = q & 3;
    int j = i - k;
    double v = 0.0;
    if (j >= 0) {
      v = Wfun(i, j) - Wfun(i + 1, j) - Wfun(i, j + 1) + Wfun(i + 1, j + 1);
      if (k == 0) v += 2.0 * 0.02 * 0.02;
    }
    Bb[i][k] = v;
  }
  __syncthreads();
  if (tid == 0) {
    for (int i = 0; i < 100; ++i) {
      for (int k = 3; k >= 1; --k) {
        int j = i - k;
        if (j < 0) { Gb[i][k] = 0.0; continue; }
        double s = Bb[i][k];
        for (int m = k + 1; m <= 3; ++m)
          if (m <= i) s -= Gb[i][m] * Gb[j][m - k];
        Gb[i][k] = s * invd[j];
      }
      double s = Bb[i][0];
      for (int m = 1; m <= 3; ++m)
        if (m <= i) s -= Gb[i][m] * Gb[i][m];
      double g = sqrt(s);
      Gb[i][0] = g;
      invd[i] = 1.0 / g;
    }
  }
  __syncthreads();
  if (tid < 100) {
    int c = tid;
    double z0 = 0, z1 = 0, z2 = 0;
    for (int i = 0; i < 100; ++i) {
      double v = (i == c ? 1.0 : 0.0) - (i == (c - 1) ? 1.0 : 0.0);
      double s = v - Gb[i][1] * z0 - Gb[i][2] * z1 - Gb[i][3] * z2;
      double z = s * invd[i];
      zbuf[i * 128 + c] = z;
      z2 = z1; z1 = z0; z0 = z;
    }
    double y0 = 0, y1 = 0, y2 = 0;
    for (int i = 99; i >= 0; --i) {
      double s = zbuf[i * 128 + c];
      if (i + 1 <= 99) s -= Gb[i + 1][1] * y0;
      if (i + 2 <= 99) s -= Gb[i + 2][2] * y1;
      if (i + 3 <= 99) s -= Gb[i + 3][3] * y2;
      double y = s * invd[i];
      zbuf[i * 128 + c] = y;
      y2 = y1; y1 = y0; y0 = y;
    }
    double ym = 0.0;
    for (int i = 0; i < 100; ++i) {
      double y = zbuf[i * 128 + c];
      cid[i * 100 + c] = y - ym;
      ym = y;
    }
  }
  __syncthreads();
  double invs = 1.0 / cid[0];
  for (int q = tid; q < 101 * 100; q += 128) {
    int k = q / 100, i = q - (q / 100) * 100;
    double val;
    if (k < 100) val = cid[i * 100 + k] - cid[i * 100] * cid[k] * invs;
    else         val = cid[i * 100] * invs;
    Qt[k * 100 + i] = (float)val;
  }
}

// =====================================================================
// quantiles + normalize (unchanged from R1)
// =====================================================================
__global__ __launch_bounds__(256) void quantile_kernel(const float* __restrict__ in,
                                                       float* __restrict__ med,
                                                       float* __restrict__ rinv)
{
  __shared__ float v[1024];
  int c = blockIdx.x, tid = threadIdx.x;
  for (int i = tid; i < 1024; i += 256) v[i] = in[i * NVARS + c];
  __syncthreads();
  for (int k = 2; k <= 1024; k <<= 1) {
    for (int j = k >> 1; j > 0; j >>= 1) {
      for (int i = tid; i < 1024; i += 256) {
        int ixj = i ^ j;
        if (ixj > i) {
          float a = v[i], b2 = v[ixj];
          bool up = ((i & k) == 0);
          if ((a > b2) == up) { v[i] = b2; v[ixj] = a; }
        }
      }
      __syncthreads();
    }
  }
  if (tid == 0) {
    float m  = v[511];
    float q1 = v[255] + 0.75f * (v[256] - v[255]);
    float q3 = v[767] + 0.25f * (v[768] - v[767]);
    float iq = q3 - q1;
    if (iq == 0.f) iq = 1.f;
    med[c] = m;
    rinv[c] = 1.f / iq;
  }
}

__global__ __launch_bounds__(256) void normalize_kernel(const float* __restrict__ in,
                                                        const float* __restrict__ med,
                                                        const float* __restrict__ rinv,
                                                        float* __restrict__ An)
{
  int idx = blockIdx.x * 256 + threadIdx.x;
  if (idx < 1024 * NVARS) {
    int c = idx % NVARS;
    An[idx] = (in[idx] - med[c]) * rinv[c];
  }
}

// =====================================================================
// f32 tiled GEMM (unchanged from R1)
// =====================================================================
template <bool RELU>
__global__ __launch_bounds__(256) void gemm_kernel(const float* __restrict__ A, int lda,
                                                   const float* __restrict__ B, int ldb,
                                                   const float* __restrict__ bias,
                                                   float* __restrict__ C, int ldc,
                                                   int N, int K)
{
  __shared__ __align__(16) float As[16][68];
  __shared__ __align__(16) float Bs[16][64];
  int tid = threadIdx.x;
  int bm = blockIdx.y * 64, bn = blockIdx.x * 64;
  int tx = tid & 15, ty = tid >> 4;
  float acc[4][4] = {};
  for (int k0 = 0; k0 < K; k0 += 16) {
    {
      int q = tid * 4;
      int m = q >> 4, kk = q & 15;
      const float* ap = A + (size_t)(bm + m) * lda + k0;
#pragma unroll
      for (int s2 = 0; s2 < 4; ++s2) {
        int kc = kk + s2;
        As[kc][m] = (k0 + kc < K) ? ap[kc] : 0.f;
      }
    }
#pragma unroll
    for (int s2 = 0; s2 < 4; ++s2) {
      int q = tid + s2 * 256;
      int kk = q >> 6, n = q & 63;
      float val = 0.f;
      if (k0 + kk < K && bn + n < N) val = B[(size_t)(k0 + kk) * ldb + bn + n];
      Bs[kk][n] = val;
    }
    __syncthreads();
#pragma unroll
    for (int kk = 0; kk < 16; ++kk) {
      float4 av = *reinterpret_cast<const float4*>(&As[kk][ty * 4]);
      float4 bv = *reinterpret_cast<const float4*>(&Bs[kk][tx * 4]);
      acc[0][0] += av.x * bv.x; acc[0][1] += av.x * bv.y; acc[0][2] += av.x * bv.z; acc[0][3] += av.x * bv.w;
      acc[1][0] += av.y * bv.x; acc[1][1] += av.y * bv.y; acc[1][2] += av.y * bv.z; acc[1][3] += av.y * bv.w;
      acc[2][0] += av.z * bv.x; acc[2][1] += av.z * bv.y; acc[2][2] += av.z * bv.z; acc[2][3] += av.z * bv.w;
      acc[3][0] += av.w * bv.x; acc[3][1] += av.w * bv.y; acc[3][2] += av.w * bv.z; acc[3][3] += av.w * bv.w;
    }
    __syncthreads();
  }
#pragma unroll
  for (int i = 0; i < 4; ++i) {
    int m = bm + ty * 4 + i;
#pragma unroll
    for (int j = 0; j < 4; ++j) {
      int n = bn + tx * 4 + j;
      if (n < N) {
        float r = acc[i][j] + bias[n];
        if (RELU) r = fmaxf(r, 0.f);
        C[(size_t)m * ldc + n] = r;
      }
    }
  }
}

// =====================================================================
// solver v2: 1 block/sample, 7 waves = 1 wave/dof. Wave-level shfl scans,
// block-cooperative Qt matvec (3 barriers/iter total).
// Local t layout per dof: vel+ [0,100) vel- [100,200) acc+ [200,299)
// acc- [299,398) jerk+ [398,496) jerk- [496,594) pos+ [594,694) pos- [694,794)
// =====================================================================
__device__ __forceinline__ float iscan(float v, int lane) {
#pragma unroll
  for (int off = 1; off < 64; off <<= 1) {
    float u = __shfl_up(v, off);
    v += (lane >= off) ? u : 0.f;
  }
  return v;
}

// w[i] for a +/- row pair. RES=false: s_minus - s_plus = relu(t-)-relu(t+)
// RES=true: res_plus - res_minus = relu(-t+)-relu(-t-)
template <bool RES>
__device__ __forceinline__ float segw(const float* td, int pi, int mi) {
  if (!RES) return fmaxf(td[mi], 0.f) - fmaxf(td[pi], 0.f);
  else      return fmaxf(-td[pi], 0.f) - fmaxf(-td[mi], 0.f);
}

// (A_dof^T w)[i] given reverse-cumsum rc of the pos part
template <bool RES>
__device__ __forceinline__ float atop(const float* td, int i, float rc) {
  float u = segw<RES>(td, i, 100 + i);                               // vel (P=I)
  float ya = (i >= 1)  ? segw<RES>(td, 200 + i - 1, 299 + i - 1) : 0.f;
  float yb = (i <= 98) ? segw<RES>(td, 200 + i,     299 + i)     : 0.f;
  u += (ya - yb) * 50.f;                                             // acc
  float z2 = (i >= 2)             ? segw<RES>(td, 398 + i - 2, 496 + i - 2) : 0.f;
  float z1 = (i >= 1 && i <= 98)  ? segw<RES>(td, 398 + i - 1, 496 + i - 1) : 0.f;
  float z0 = (i <= 97)            ? segw<RES>(td, 398 + i,     496 + i)     : 0.f;
  u += (z2 - 2.f * z1 + z0) * 2500.f;                                // jerk
  u += 0.02f * rc;                                                   // pos
  return u;
}

__global__ __launch_bounds__(448) void solver_kernel(const float* __restrict__ out2,
                                                     const float* __restrict__ input,
                                                     const float* __restrict__ theta,
                                                     const float* __restrict__ vstart,
                                                     const float* __restrict__ Qtg,
                                                     float* __restrict__ out)
{
  __shared__ float t_l[7][794];
  __shared__ __align__(16) float ru_t[101][8];   // [k][dof], [k][7] pad
  __shared__ float pm[4][700];                   // matvec partials; pm[0] holds xi after combine
  __shared__ float part[7][20][3];               // per-dof per-iter r2, ds2, dl2
  __shared__ float prfp[40];

  const int b = blockIdx.x, tid = threadIdx.x;
  const int d = tid >> 6, l = tid & 63;
  const bool hi = (l < 36);
  const int i2 = 64 + l;
  float* td = &t_l[d][0];
  const float* orow = out2 + (size_t)b * OUTC;
  const float* srow = orow + 700;
  const float th = theta[b];

  // ---- init: lam/xs regs, t in LDS, ru_t[100] = v_start ----
  float lam0 = orow[d * 100 + l];
  float xs0  = input[(size_t)b * NVARS + d * 100 + l];
  float lam1 = 0.f, xs1 = 0.f;
  if (hi) {
    lam1 = orow[d * 100 + i2];
    xs1  = input[(size_t)b * NVARS + d * 100 + i2];
  }
  {
    int vb = d * 200, ab = 1400 + d * 198, jb = 2786 + d * 196, pb = 4158 + d * 200;
    td[l]       = fmaxf(srow[vb + l], 0.f);
    td[100 + l] = fmaxf(srow[vb + 100 + l], 0.f);
    if (l <= 98) { td[200 + l] = fmaxf(srow[ab + l], 0.f);      td[299 + l] = fmaxf(srow[ab + 99 + l], 0.f); }
    if (l <= 97) { td[398 + l] = fmaxf(srow[jb + l], 0.f);      td[496 + l] = fmaxf(srow[jb + 98 + l], 0.f); }
    td[594 + l] = fmaxf(srow[pb + l], 0.f);
    td[694 + l] = fmaxf(srow[pb + 100 + l], 0.f);
    if (hi) {
      td[i2]       = fmaxf(srow[vb + i2], 0.f);
      td[100 + i2] = fmaxf(srow[vb + 100 + i2], 0.f);
      if (l <= 34) { td[200 + i2] = fmaxf(srow[ab + i2], 0.f);  td[299 + i2] = fmaxf(srow[ab + 99 + i2], 0.f); }
      if (l <= 33) { td[398 + i2] = fmaxf(srow[jb + i2], 0.f);  td[496 + i2] = fmaxf(srow[jb + 98 + i2], 0.f); }
      td[594 + i2] = fmaxf(srow[pb + i2], 0.f);
      td[694 + i2] = fmaxf(srow[pb + 100 + i2], 0.f);
    }
  }
  if (l == 0) ru_t[100][d] = vstart[b * 7 + d];

  for (int it = 0; it < MAXIT; ++it) {
    // ---- phase A (per-wave): ru = lam + xs + A^T(b - s) ----
    {
      float pa0 = segw<false>(td, 594 + l, 694 + l);
      float pa1 = hi ? segw<false>(td, 594 + i2, 694 + i2) : 0.f;
      if (d == 3) { pa0 -= 2.f * th; if (hi) pa1 -= 2.f * th; }   // reference b_control split
      float s0i = iscan(pa0, l);
      float tot0 = __shfl(s0i, 63);
      float s1i = iscan(hi ? pa1 : 0.f, l) + tot0;
      float S = __shfl(s1i, 35);
      float rc0 = S - s0i + pa0;
      float ru0 = lam0 + xs0 + atop<false>(td, l, rc0);
      ru_t[l][d] = ru0;
      if (hi) {
        float rc1 = S - s1i + pa1;
        float ru1 = lam1 + xs1 + atop<false>(td, i2, rc1);
        ru_t[i2][d] = ru1;
      }
    }
    __syncthreads();   // barrier 1: ru ready for all dofs

    // ---- phase B (cooperative): xi = Qtop @ [ru; v], 100 rows x 4 k-chunks ----
    {
      int kc = tid / 112, r = tid - kc * 112;
      if (r < 100) {
        float acc[7] = {0.f, 0.f, 0.f, 0.f, 0.f, 0.f, 0.f};
        int k0 = kc * 25, k1 = (kc == 3) ? 101 : k0 + 25;
        for (int k = k0; k < k1; ++k) {
          float qv = Qtg[k * 100 + r];
          float4 ra = *reinterpret_cast<const float4*>(&ru_t[k][0]);
          float4 rb = *reinterpret_cast<const float4*>(&ru_t[k][4]);
          acc[0] += qv * ra.x; acc[1] += qv * ra.y; acc[2] += qv * ra.z; acc[3] += qv * ra.w;
          acc[4] += qv * rb.x; acc[5] += qv * rb.y; acc[6] += qv * rb.z;
        }
#pragma unroll
        for (int dd = 0; dd < 7; ++dd) pm[kc][dd * 100 + r] = acc[dd];
      }
    }
    __syncthreads();   // barrier 2: partials ready
    {
      int p = tid;
      if (p < 700) { float v = pm[0][p] + pm[1][p] + pm[2][p] + pm[3][p]; pm[0][p] = v; }
      p = tid + 448;
      if (p < 700) { float v = pm[0][p] + pm[1][p] + pm[2][p] + pm[3][p]; pm[0][p] = v; }
    }
    __syncthreads();   // barrier 3: xi ready in pm[0]

    // ---- phase C (per-wave): t = b - A xi; r2, ds2 ----
    float r2 = 0.f, ds2 = 0.f, dl2 = 0.f;
    {
      const float* xid = &pm[0][d * 100];
      float x0 = xid[l], x1 = hi ? xid[i2] : 0.f;
      float c0i = iscan(x0, l);
      float tt0 = __shfl(c0i, 63);
      float c1i = iscan(hi ? x1 : 0.f, l) + tt0;
      float bp = (d <= 3) ? (3.14f - th) : (3.14f + th);   // pos+ rows
      float bm2 = (d < 3) ? (3.14f - th) : (3.14f + th);   // pos- rows
#define UPD(idx, tnew) { int _ix = (idx); float _tn = (tnew); float _to = td[_ix]; \
      float _dd = fmaxf(_to, 0.f) - fmaxf(_tn, 0.f); ds2 += _dd * _dd; \
      float _rr = fmaxf(-_tn, 0.f); r2 += _rr * _rr; td[_ix] = _tn; }
      UPD(l, 1.f - x0) UPD(100 + l, 1.f + x0)
      if (hi) { UPD(i2, 1.f - x1) UPD(100 + i2, 1.f + x1) }
      if (l <= 98) { float a = (xid[l + 1] - x0) * 50.f; UPD(200 + l, 2.f - a) UPD(299 + l, 2.f + a) }
      if (hi && l <= 34) { float a = (xid[i2 + 1] - x1) * 50.f; UPD(200 + i2, 2.f - a) UPD(299 + i2, 2.f + a) }
      if (l <= 97) { float jr = (xid[l + 2] - 2.f * xid[l + 1] + x0) * 2500.f; UPD(398 + l, 5.f - jr) UPD(496 + l, 5.f + jr) }
      if (hi && l <= 33) { float jr = (xid[i2 + 2] - 2.f * xid[i2 + 1] + x1) * 2500.f; UPD(398 + i2, 5.f - jr) UPD(496 + i2, 5.f + jr) }
      UPD(594 + l, bp - 0.02f * c0i) UPD(694 + l, bm2 + 0.02f * c0i)
      if (hi) { UPD(594 + i2, bp - 0.02f * c1i) UPD(694 + i2, bm2 + 0.02f * c1i) }
#undef UPD
    }

    // ---- phase D (per-wave): g = A^T relu(-t); lam -= g ----
    {
      float pa0 = segw<true>(td, 594 + l, 694 + l);
      float pa1 = hi ? segw<true>(td, 594 + i2, 694 + i2) : 0.f;
      float s0i = iscan(pa0, l);
      float tot0 = __shfl(s0i, 63);
      float s1i = iscan(hi ? pa1 : 0.f, l) + tot0;
      float S = __shfl(s1i, 35);
      float rc0 = S - s0i + pa0;
      float g0 = atop<true>(td, l, rc0);
      lam0 -= g0; dl2 += g0 * g0;
      if (hi) {
        float rc1 = S - s1i + pa1;
        float g1 = atop<true>(td, i2, rc1);
        lam1 -= g1; dl2 += g1 * g1;
      }
    }

    // ---- per-wave norm reduce ----
#pragma unroll
    for (int o = 32; o > 0; o >>= 1) {
      r2  += __shfl_down(r2, o);
      ds2 += __shfl_down(ds2, o);
      dl2 += __shfl_down(dl2, o);
    }
    if (l == 0) { part[d][it][0] = r2; part[d][it][1] = ds2; part[d][it][2] = dl2; }
  }

  __syncthreads();
  // xi output
  {
    float* xout = out + (size_t)b * NVARS + d * 100;
    const float* xid = &pm[0][d * 100];
    xout[l] = xid[l];
    if (hi) xout[i2] = xid[i2];
  }
  if (tid < 20) {
    int it = tid;
    float R2 = 0.f, DS2 = 0.f, DL2 = 0.f;
    for (int dd = 0; dd < 7; ++dd) {
      R2 += part[dd][it][0]; DS2 += part[dd][it][1]; DL2 += part[dd][it][2];
    }
    float pr = sqrtf(R2), fp = sqrtf(DL2) + sqrtf(DS2);
    out[718848 + it * 1024 + b] = pr;
    out[739328 + it * 1024 + b] = fp;
    prfp[it] = pr; prfp[20 + it] = fp;
  }
  __syncthreads();
  if (tid == 0) {
    float ap = 0.f, af = 0.f;
    for (int it = 0; it < 20; ++it) { ap += prfp[it]; af += prfp[20 + it]; }
    out[716800 + b] = af / 20.f;
    out[717824 + b] = ap / 20.f;
  }
}

// =====================================================================
extern "C" void kernel_launch(void* const* d_in, const int* in_sizes, int n_in,
                              void* d_out, int out_size, void* d_ws, size_t ws_size,
                              hipStream_t stream) {
  (void)in_sizes; (void)n_in; (void)out_size;
  const float* input  = (const float*)d_in[0];
  const float* theta  = (const float*)d_in[1];
  const float* vstart = (const float*)d_in[2];
  const float* W1     = (const float*)d_in[3];
  const float* b1     = (const float*)d_in[4];
  const float* W2     = (const float*)d_in[5];
  const float* b2     = (const float*)d_in[6];
  float* out = (float*)d_out;

  double* wsd  = (double*)d_ws;
  double* zbuf = wsd;
  double* cid  = wsd + 12800;
  float* wsf  = (float*)d_ws;
  float* Qt   = wsf + 45600;
  float* med  = wsf + 55704;
  float* rinv = wsf + 56408;
  float* An   = wsf + 57112;
  float* h    = wsf + 773912;
  float* out2 = wsf + 1822488;
  if (ws_size < (size_t)(1822488 + 6408192) * 4) return;

  hipLaunchKernelGGL(qinv_kernel, dim3(1), dim3(128), 0, stream, zbuf, cid, Qt);
  hipLaunchKernelGGL(quantile_kernel, dim3(700), dim3(256), 0, stream, input, med, rinv);
  hipLaunchKernelGGL(normalize_kernel, dim3(2800), dim3(256), 0, stream, input, med, rinv, An);
  hipLaunchKernelGGL((gemm_kernel<true>), dim3(16, 16), dim3(256), 0, stream,
                     An, NVARS, W1, 1024, b1, h, 1024, 1024, NVARS);
  hipLaunchKernelGGL((gemm_kernel<false>), dim3(98, 16), dim3(256), 0, stream,
                     h, 1024, W2 + 700, 6958, b2 + 700, out2, OUTC, OUTC, 1024);
  hipLaunchKernelGGL(solver_kernel, dim3(1024), dim3(448), 0, stream,
                     out2, input, theta, vstart, Qt, out);
}

// Round 3
// 555.786 us; speedup vs baseline: 1.9153x; 1.6242x over previous
//
#include <hip/hip_runtime.h>

// ---------------- problem constants ----------------
#define NVARS 700
#define MC    5558
#define MAXIT 20

typedef __attribute__((ext_vector_type(8))) short bf16x8;
typedef __attribute__((ext_vector_type(4))) float f32x4;

__device__ __forceinline__ ushort f2bf(float x) {
  unsigned u = __float_as_uint(x);
  return (ushort)((u + 0x7FFFu + ((u >> 16) & 1u)) >> 16);
}

// =====================================================================
// qinv kernel (unchanged): Qt[k*100+i], k in [0,101)
// =====================================================================
__device__ __forceinline__ double Wfun(int a, int b) {
  if (a < 0 || a > 99 || b < 0 || b > 99) return 0.0;
  int d = a - b; if (d < 0) d = -d;
  int l = a < b ? a : b;
  const double iT2 = 2500.0;
  const double iT4 = 6250000.0;
  double w = 0.0;
  if (d == 0) {
    w = 3.0;
    w += 2.0 * iT2 * (double)((a <= 98 ? 1 : 0) + (a >= 1 ? 1 : 0));
    double dd = (double)(((a - 2) >= 0 && (a - 2) <= 97) ? 1 : 0)
              + 4.0 * (double)(((a - 1) >= 0 && (a - 1) <= 97) ? 1 : 0)
              + (double)((a <= 97) ? 1 : 0);
    w += 2.0 * iT4 * dd;
  } else if (d == 1) {
    w = -2.0 * iT2;
    double dd = -2.0 * (double)(((l - 1) >= 0 && (l - 1) <= 97) ? 1 : 0)
                - 2.0 * (double)((l <= 97) ? 1 : 0);
    w += 2.0 * iT4 * dd;
  } else if (d == 2) {
    w = 2.0 * iT4 * (double)((l <= 97) ? 1 : 0);
  }
  return w;
}

__global__ __launch_bounds__(128) void qinv_kernel(double* __restrict__ zbuf,
                                                   double* __restrict__ cid,
                                                   float* __restrict__ Qt)
{
  __shared__ double Bb[100][4];
  __shared__ double Gb[100][4];
  __shared__ double invd[100];
  int tid = threadIdx.x;
  for (int q = tid; q < 400; q += 128) {
    int i = q >> 2, k = q & 3;
    int j = i - k;
    double v = 0.0;
    if (j >= 0) {
      v = Wfun(i, j) - Wfun(i + 1, j) - Wfun(i, j + 1) + Wfun(i + 1, j + 1);
      if (k == 0) v += 2.0 * 0.02 * 0.02;
    }
    Bb[i][k] = v;
  }
  __syncthreads();
  if (tid == 0) {
    for (int i = 0; i < 100; ++i) {
      for (int k = 3; k >= 1; --k) {
        int j = i - k;
        if (j < 0) { Gb[i][k] = 0.0; continue; }
        double s = Bb[i][k];
        for (int m = k + 1; m <= 3; ++m)
          if (m <= i) s -= Gb[i][m] * Gb[j][m - k];
        Gb[i][k] = s * invd[j];
      }
      double s = Bb[i][0];
      for (int m = 1; m <= 3; ++m)
        if (m <= i) s -= Gb[i][m] * Gb[i][m];
      double g = sqrt(s);
      Gb[i][0] = g;
      invd[i] = 1.0 / g;
    }
  }
  __syncthreads();
  if (tid < 100) {
    int c = tid;
    double z0 = 0, z1 = 0, z2 = 0;
    for (int i = 0; i < 100; ++i) {
      double v = (i == c ? 1.0 : 0.0) - (i == (c - 1) ? 1.0 : 0.0);
      double s = v - Gb[i][1] * z0 - Gb[i][2] * z1 - Gb[i][3] * z2;
      double z = s * invd[i];
      zbuf[i * 128 + c] = z;
      z2 = z1; z1 = z0; z0 = z;
    }
    double y0 = 0, y1 = 0, y2 = 0;
    for (int i = 99; i >= 0; --i) {
      double s = zbuf[i * 128 + c];
      if (i + 1 <= 99) s -= Gb[i + 1][1] * y0;
      if (i + 2 <= 99) s -= Gb[i + 2][2] * y1;
      if (i + 3 <= 99) s -= Gb[i + 3][3] * y2;
      double y = s * invd[i];
      zbuf[i * 128 + c] = y;
      y2 = y1; y1 = y0; y0 = y;
    }
    double ym = 0.0;
    for (int i = 0; i < 100; ++i) {
      double y = zbuf[i * 128 + c];
      cid[i * 100 + c] = y - ym;
      ym = y;
    }
  }
  __syncthreads();
  double invs = 1.0 / cid[0];
  for (int q = tid; q < 101 * 100; q += 128) {
    int k = q / 100, i = q - (q / 100) * 100;
    double val;
    if (k < 100) val = cid[i * 100 + k] - cid[i * 100] * cid[k] * invs;
    else         val = cid[i * 100] * invs;
    Qt[k * 100 + i] = (float)val;
  }
}

// =====================================================================
// quantiles (unchanged)
// =====================================================================
__global__ __launch_bounds__(256) void quantile_kernel(const float* __restrict__ in,
                                                       float* __restrict__ med,
                                                       float* __restrict__ rinv)
{
  __shared__ float v[1024];
  int c = blockIdx.x, tid = threadIdx.x;
  for (int i = tid; i < 1024; i += 256) v[i] = in[i * NVARS + c];
  __syncthreads();
  for (int k = 2; k <= 1024; k <<= 1) {
    for (int j = k >> 1; j > 0; j >>= 1) {
      for (int i = tid; i < 1024; i += 256) {
        int ixj = i ^ j;
        if (ixj > i) {
          float a = v[i], b2 = v[ixj];
          bool up = ((i & k) == 0);
          if ((a > b2) == up) { v[i] = b2; v[ixj] = a; }
        }
      }
      __syncthreads();
    }
  }
  if (tid == 0) {
    float m  = v[511];
    float q1 = v[255] + 0.75f * (v[256] - v[255]);
    float q3 = v[767] + 0.25f * (v[768] - v[767]);
    float iq = q3 - q1;
    if (iq == 0.f) iq = 1.f;
    med[c] = m;
    rinv[c] = 1.f / iq;
  }
}

// ---- new path: normalize + split to bf16 hi/lo, padded K=704 ----
__global__ __launch_bounds__(256) void normalize_split(const float* __restrict__ in,
                                                       const float* __restrict__ med,
                                                       const float* __restrict__ rinv,
                                                       ushort* __restrict__ Ah,
                                                       ushort* __restrict__ Al)
{
  int idx = blockIdx.x * 256 + threadIdx.x;
  if (idx >= 1024 * 704) return;
  int r = idx / 704, c = idx - r * 704;
  float v = 0.f;
  if (c < 700) v = (in[r * NVARS + c] - med[c]) * rinv[c];
  ushort h = f2bf(v);
  float fh = __uint_as_float(((unsigned)h) << 16);
  Ah[idx] = h;
  Al[idx] = f2bf(v - fh);
}

// ---- transpose + split: dst[n][k] = src[k][col0+n], zero padded ----
__global__ __launch_bounds__(256) void tsplit(const float* __restrict__ src,
                                              int srows, int scols, int sld, int col0,
                                              ushort* __restrict__ dh,
                                              ushort* __restrict__ dl, int dld)
{
  __shared__ float tile[32][33];
  int k0 = blockIdx.x * 32, n0 = blockIdx.y * 32;
  int tx = threadIdx.x, ty = threadIdx.y;   // (32, 8)
  for (int i = ty; i < 32; i += 8) {
    int k = k0 + i, c = col0 + n0 + tx;
    tile[i][tx] = (k < srows && c < scols) ? src[(size_t)k * sld + c] : 0.f;
  }
  __syncthreads();
  for (int i = ty; i < 32; i += 8) {
    int n = n0 + i, k = k0 + tx;
    float v = tile[tx][i];
    ushort h = f2bf(v);
    float fh = __uint_as_float(((unsigned)h) << 16);
    dh[(size_t)n * dld + k] = h;
    dl[(size_t)n * dld + k] = f2bf(v - fh);
  }
}

// =====================================================================
// MFMA GEMM, bf16 hi/lo split (3 products ~= f32 accuracy).
// C[M x Np] = A[M x Kp] @ B^T where B given n-major [Np][Kp].
// 128x128 tiles, BK=32, 256 thr (4 waves 2x2), LDS stride 40 elems (80B).
// MODE 0: Cf = acc + bias (guarded) ; MODE 1: relu(acc+bias) -> hi/lo bf16
// =====================================================================
template <int MODE>
__global__ __launch_bounds__(256) void gemm_mfma(
    const ushort* __restrict__ Agh, const ushort* __restrict__ Agl,
    const ushort* __restrict__ Bgh, const ushort* __restrict__ Bgl,
    const float* __restrict__ bias, int bias_n,
    float* __restrict__ Cf, ushort* __restrict__ Chi, ushort* __restrict__ Clo,
    int Kp, int ldc)
{
  __shared__ __align__(16) ushort Ash[128 * 40];
  __shared__ __align__(16) ushort Asl[128 * 40];
  __shared__ __align__(16) ushort Bsh[128 * 40];
  __shared__ __align__(16) ushort Bsl[128 * 40];

  const int t = threadIdx.x;
  const int srow = t >> 1;            // staging row 0..127
  const int sc0 = (t & 1) * 2;        // 16B-chunk base (of 4 per row)
  const size_t bm = (size_t)blockIdx.y * 128;
  const size_t bn = (size_t)blockIdx.x * 128;

  const ushort* gAh = Agh + (bm + srow) * Kp + sc0 * 8;
  const ushort* gAl = Agl + (bm + srow) * Kp + sc0 * 8;
  const ushort* gBh = Bgh + (bn + srow) * Kp + sc0 * 8;
  const ushort* gBl = Bgl + (bn + srow) * Kp + sc0 * 8;

  const int w = t >> 6, lane = t & 63;
  const int wr = w >> 1, wc = w & 1;
  const int fr = lane & 15, fg = lane >> 4;

  f32x4 acc[4][4];
#pragma unroll
  for (int a = 0; a < 4; ++a)
#pragma unroll
    for (int b = 0; b < 4; ++b) acc[a][b] = (f32x4){0.f, 0.f, 0.f, 0.f};

  const int nk = Kp >> 5;
  uint4 rA0, rA1, rAl0, rAl1, rB0, rB1, rBl0, rBl1;
  {
    rA0  = *(const uint4*)(gAh);      rA1  = *(const uint4*)(gAh + 8);
    rAl0 = *(const uint4*)(gAl);      rAl1 = *(const uint4*)(gAl + 8);
    rB0  = *(const uint4*)(gBh);      rB1  = *(const uint4*)(gBh + 8);
    rBl0 = *(const uint4*)(gBl);      rBl1 = *(const uint4*)(gBl + 8);
  }
  const int woff = srow * 40 + sc0 * 8;

  for (int kt = 0;; ++kt) {
    __syncthreads();                  // previous frag reads complete
    *(uint4*)&Ash[woff] = rA0;  *(uint4*)&Ash[woff + 8] = rA1;
    *(uint4*)&Asl[woff] = rAl0; *(uint4*)&Asl[woff + 8] = rAl1;
    *(uint4*)&Bsh[woff] = rB0;  *(uint4*)&Bsh[woff + 8] = rB1;
    *(uint4*)&Bsl[woff] = rBl0; *(uint4*)&Bsl[woff + 8] = rBl1;
    __syncthreads();
    if (kt + 1 < nk) {
      int ko = (kt + 1) * 32;
      rA0  = *(const uint4*)(gAh + ko);      rA1  = *(const uint4*)(gAh + ko + 8);
      rAl0 = *(const uint4*)(gAl + ko);      rAl1 = *(const uint4*)(gAl + ko + 8);
      rB0  = *(const uint4*)(gBh + ko);      rB1  = *(const uint4*)(gBh + ko + 8);
      rBl0 = *(const uint4*)(gBl + ko);      rBl1 = *(const uint4*)(gBl + ko + 8);
    }
    bf16x8 fah[4], fal[4], fbh[4], fbl[4];
#pragma unroll
    for (int mf = 0; mf < 4; ++mf) {
      int off = (wr * 64 + mf * 16 + fr) * 40 + fg * 8;
      fah[mf] = *(const bf16x8*)&Ash[off];
      fal[mf] = *(const bf16x8*)&Asl[off];
    }
#pragma unroll
    for (int nf = 0; nf < 4; ++nf) {
      int off = (wc * 64 + nf * 16 + fr) * 40 + fg * 8;
      fbh[nf] = *(const bf16x8*)&Bsh[off];
      fbl[nf] = *(const bf16x8*)&Bsl[off];
    }
#pragma unroll
    for (int mf = 0; mf < 4; ++mf)
#pragma unroll
      for (int nf = 0; nf < 4; ++nf) {
        acc[mf][nf] = __builtin_amdgcn_mfma_f32_16x16x32_bf16(fah[mf], fbh[nf], acc[mf][nf], 0, 0, 0);
        acc[mf][nf] = __builtin_amdgcn_mfma_f32_16x16x32_bf16(fah[mf], fbl[nf], acc[mf][nf], 0, 0, 0);
        acc[mf][nf] = __builtin_amdgcn_mfma_f32_16x16x32_bf16(fal[mf], fbh[nf], acc[mf][nf], 0, 0, 0);
      }
    if (kt + 1 >= nk) break;
  }

#pragma unroll
  for (int mf = 0; mf < 4; ++mf)
#pragma unroll
    for (int nf = 0; nf < 4; ++nf) {
      int col = (int)bn + wc * 64 + nf * 16 + fr;
      int rowb = (int)bm + wr * 64 + mf * 16 + fg * 4;
#pragma unroll
      for (int j = 0; j < 4; ++j) {
        int row = rowb + j;
        float v = acc[mf][nf][j];
        if (MODE == 0) {
          float bv = (col < bias_n) ? bias[col] : 0.f;
          Cf[(size_t)row * ldc + col] = v + bv;
        } else {
          float r = fmaxf(v + bias[col], 0.f);
          ushort h = f2bf(r);
          float fh = __uint_as_float(((unsigned)h) << 16);
          Chi[(size_t)row * ldc + col] = h;
          Clo[(size_t)row * ldc + col] = f2bf(r - fh);
        }
      }
    }
}

// =====================================================================
// fallback path (R2): f32 normalize + SIMT GEMM
// =====================================================================
__global__ __launch_bounds__(256) void normalize_kernel(const float* __restrict__ in,
                                                        const float* __restrict__ med,
                                                        const float* __restrict__ rinv,
                                                        float* __restrict__ An)
{
  int idx = blockIdx.x * 256 + threadIdx.x;
  if (idx < 1024 * NVARS) {
    int c = idx % NVARS;
    An[idx] = (in[idx] - med[c]) * rinv[c];
  }
}

template <bool RELU>
__global__ __launch_bounds__(256) void gemm_kernel(const float* __restrict__ A, int lda,
                                                   const float* __restrict__ B, int ldb,
                                                   const float* __restrict__ bias,
                                                   float* __restrict__ C, int ldc,
                                                   int N, int K)
{
  __shared__ __align__(16) float As[16][68];
  __shared__ __align__(16) float Bs[16][64];
  int tid = threadIdx.x;
  int bm = blockIdx.y * 64, bn = blockIdx.x * 64;
  int tx = tid & 15, ty = tid >> 4;
  float acc[4][4] = {};
  for (int k0 = 0; k0 < K; k0 += 16) {
    {
      int q = tid * 4;
      int m = q >> 4, kk = q & 15;
      const float* ap = A + (size_t)(bm + m) * lda + k0;
#pragma unroll
      for (int s2 = 0; s2 < 4; ++s2) {
        int kc = kk + s2;
        As[kc][m] = (k0 + kc < K) ? ap[kc] : 0.f;
      }
    }
#pragma unroll
    for (int s2 = 0; s2 < 4; ++s2) {
      int q = tid + s2 * 256;
      int kk = q >> 6, n = q & 63;
      float val = 0.f;
      if (k0 + kk < K && bn + n < N) val = B[(size_t)(k0 + kk) * ldb + bn + n];
      Bs[kk][n] = val;
    }
    __syncthreads();
#pragma unroll
    for (int kk = 0; kk < 16; ++kk) {
      float4 av = *reinterpret_cast<const float4*>(&As[kk][ty * 4]);
      float4 bv = *reinterpret_cast<const float4*>(&Bs[kk][tx * 4]);
      acc[0][0] += av.x * bv.x; acc[0][1] += av.x * bv.y; acc[0][2] += av.x * bv.z; acc[0][3] += av.x * bv.w;
      acc[1][0] += av.y * bv.x; acc[1][1] += av.y * bv.y; acc[1][2] += av.y * bv.z; acc[1][3] += av.y * bv.w;
      acc[2][0] += av.z * bv.x; acc[2][1] += av.z * bv.y; acc[2][2] += av.z * bv.z; acc[2][3] += av.z * bv.w;
      acc[3][0] += av.w * bv.x; acc[3][1] += av.w * bv.y; acc[3][2] += av.w * bv.z; acc[3][3] += av.w * bv.w;
    }
    __syncthreads();
  }
#pragma unroll
  for (int i = 0; i < 4; ++i) {
    int m = bm + ty * 4 + i;
#pragma unroll
    for (int j = 0; j < 4; ++j) {
      int n = bn + tx * 4 + j;
      if (n < N) {
        float r = acc[i][j] + bias[n];
        if (RELU) r = fmaxf(r, 0.f);
        C[(size_t)m * ldc + n] = r;
      }
    }
  }
}

// =====================================================================
// solver (R2, + out2 leading-dim param)
// =====================================================================
__device__ __forceinline__ float iscan(float v, int lane) {
#pragma unroll
  for (int off = 1; off < 64; off <<= 1) {
    float u = __shfl_up(v, off);
    v += (lane >= off) ? u : 0.f;
  }
  return v;
}

template <bool RES>
__device__ __forceinline__ float segw(const float* td, int pi, int mi) {
  if (!RES) return fmaxf(td[mi], 0.f) - fmaxf(td[pi], 0.f);
  else      return fmaxf(-td[pi], 0.f) - fmaxf(-td[mi], 0.f);
}

template <bool RES>
__device__ __forceinline__ float atop(const float* td, int i, float rc) {
  float u = segw<RES>(td, i, 100 + i);
  float ya = (i >= 1)  ? segw<RES>(td, 200 + i - 1, 299 + i - 1) : 0.f;
  float yb = (i <= 98) ? segw<RES>(td, 200 + i,     299 + i)     : 0.f;
  u += (ya - yb) * 50.f;
  float z2 = (i >= 2)             ? segw<RES>(td, 398 + i - 2, 496 + i - 2) : 0.f;
  float z1 = (i >= 1 && i <= 98)  ? segw<RES>(td, 398 + i - 1, 496 + i - 1) : 0.f;
  float z0 = (i <= 97)            ? segw<RES>(td, 398 + i,     496 + i)     : 0.f;
  u += (z2 - 2.f * z1 + z0) * 2500.f;
  u += 0.02f * rc;
  return u;
}

__global__ __launch_bounds__(448) void solver_kernel(const float* __restrict__ out2,
                                                     const float* __restrict__ input,
                                                     const float* __restrict__ theta,
                                                     const float* __restrict__ vstart,
                                                     const float* __restrict__ Qtg,
                                                     float* __restrict__ out, int ldo)
{
  __shared__ float t_l[7][794];
  __shared__ __align__(16) float ru_t[101][8];
  __shared__ float pm[4][700];
  __shared__ float part[7][20][3];
  __shared__ float prfp[40];

  const int b = blockIdx.x, tid = threadIdx.x;
  const int d = tid >> 6, l = tid & 63;
  const bool hi = (l < 36);
  const int i2 = 64 + l;
  float* td = &t_l[d][0];
  const float* orow = out2 + (size_t)b * ldo;
  const float* srow = orow + 700;
  const float th = theta[b];

  float lam0 = orow[d * 100 + l];
  float xs0  = input[(size_t)b * NVARS + d * 100 + l];
  float lam1 = 0.f, xs1 = 0.f;
  if (hi) {
    lam1 = orow[d * 100 + i2];
    xs1  = input[(size_t)b * NVARS + d * 100 + i2];
  }
  {
    int vb = d * 200, ab = 1400 + d * 198, jb = 2786 + d * 196, pb = 4158 + d * 200;
    td[l]       = fmaxf(srow[vb + l], 0.f);
    td[100 + l] = fmaxf(srow[vb + 100 + l], 0.f);
    if (l <= 98) { td[200 + l] = fmaxf(srow[ab + l], 0.f);      td[299 + l] = fmaxf(srow[ab + 99 + l], 0.f); }
    if (l <= 97) { td[398 + l] = fmaxf(srow[jb + l], 0.f);      td[496 + l] = fmaxf(srow[jb + 98 + l], 0.f); }
    td[594 + l] = fmaxf(srow[pb + l], 0.f);
    td[694 + l] = fmaxf(srow[pb + 100 + l], 0.f);
    if (hi) {
      td[i2]       = fmaxf(srow[vb + i2], 0.f);
      td[100 + i2] = fmaxf(srow[vb + 100 + i2], 0.f);
      if (l <= 34) { td[200 + i2] = fmaxf(srow[ab + i2], 0.f);  td[299 + i2] = fmaxf(srow[ab + 99 + i2], 0.f); }
      if (l <= 33) { td[398 + i2] = fmaxf(srow[jb + i2], 0.f);  td[496 + i2] = fmaxf(srow[jb + 98 + i2], 0.f); }
      td[594 + i2] = fmaxf(srow[pb + i2], 0.f);
      td[694 + i2] = fmaxf(srow[pb + 100 + i2], 0.f);
    }
  }
  if (l == 0) ru_t[100][d] = vstart[b * 7 + d];

  for (int it = 0; it < MAXIT; ++it) {
    {
      float pa0 = segw<false>(td, 594 + l, 694 + l);
      float pa1 = hi ? segw<false>(td, 594 + i2, 694 + i2) : 0.f;
      if (d == 3) { pa0 -= 2.f * th; if (hi) pa1 -= 2.f * th; }
      float s0i = iscan(pa0, l);
      float tot0 = __shfl(s0i, 63);
      float s1i = iscan(hi ? pa1 : 0.f, l) + tot0;
      float S = __shfl(s1i, 35);
      float rc0 = S - s0i + pa0;
      float ru0 = lam0 + xs0 + atop<false>(td, l, rc0);
      ru_t[l][d] = ru0;
      if (hi) {
        float rc1 = S - s1i + pa1;
        float ru1 = lam1 + xs1 + atop<false>(td, i2, rc1);
        ru_t[i2][d] = ru1;
      }
    }
    __syncthreads();

    {
      int kc = tid / 112, r = tid - kc * 112;
      if (r < 100) {
        float acc[7] = {0.f, 0.f, 0.f, 0.f, 0.f, 0.f, 0.f};
        int k0 = kc * 25, k1 = (kc == 3) ? 101 : k0 + 25;
        for (int k = k0; k < k1; ++k) {
          float qv = Qtg[k * 100 + r];
          float4 ra = *reinterpret_cast<const float4*>(&ru_t[k][0]);
          float4 rb = *reinterpret_cast<const float4*>(&ru_t[k][4]);
          acc[0] += qv * ra.x; acc[1] += qv * ra.y; acc[2] += qv * ra.z; acc[3] += qv * ra.w;
          acc[4] += qv * rb.x; acc[5] += qv * rb.y; acc[6] += qv * rb.z;
        }
#pragma unroll
        for (int dd = 0; dd < 7; ++dd) pm[kc][dd * 100 + r] = acc[dd];
      }
    }
    __syncthreads();
    {
      int p = tid;
      if (p < 700) { float v = pm[0][p] + pm[1][p] + pm[2][p] + pm[3][p]; pm[0][p] = v; }
      p = tid + 448;
      if (p < 700) { float v = pm[0][p] + pm[1][p] + pm[2][p] + pm[3][p]; pm[0][p] = v; }
    }
    __syncthreads();

    float r2 = 0.f, ds2 = 0.f, dl2 = 0.f;
    {
      const float* xid = &pm[0][d * 100];
      float x0 = xid[l], x1 = hi ? xid[i2] : 0.f;
      float c0i = iscan(x0, l);
      float tt0 = __shfl(c0i, 63);
      float c1i = iscan(hi ? x1 : 0.f, l) + tt0;
      float bp = (d <= 3) ? (3.14f - th) : (3.14f + th);
      float bm2 = (d < 3) ? (3.14f - th) : (3.14f + th);
#define UPD(idx, tnew) { int _ix = (idx); float _tn = (tnew); float _to = td[_ix]; \
      float _dd = fmaxf(_to, 0.f) - fmaxf(_tn, 0.f); ds2 += _dd * _dd; \
      float _rr = fmaxf(-_tn, 0.f); r2 += _rr * _rr; td[_ix] = _tn; }
      UPD(l, 1.f - x0) UPD(100 + l, 1.f + x0)
      if (hi) { UPD(i2, 1.f - x1) UPD(100 + i2, 1.f + x1) }
      if (l <= 98) { float a = (xid[l + 1] - x0) * 50.f; UPD(200 + l, 2.f - a) UPD(299 + l, 2.f + a) }
      if (hi && l <= 34) { float a = (xid[i2 + 1] - x1) * 50.f; UPD(200 + i2, 2.f - a) UPD(299 + i2, 2.f + a) }
      if (l <= 97) { float jr = (xid[l + 2] - 2.f * xid[l + 1] + x0) * 2500.f; UPD(398 + l, 5.f - jr) UPD(496 + l, 5.f + jr) }
      if (hi && l <= 33) { float jr = (xid[i2 + 2] - 2.f * xid[i2 + 1] + x1) * 2500.f; UPD(398 + i2, 5.f - jr) UPD(496 + i2, 5.f + jr) }
      UPD(594 + l, bp - 0.02f * c0i) UPD(694 + l, bm2 + 0.02f * c0i)
      if (hi) { UPD(594 + i2, bp - 0.02f * c1i) UPD(694 + i2, bm2 + 0.02f * c1i) }
#undef UPD
    }

    {
      float pa0 = segw<true>(td, 594 + l, 694 + l);
      float pa1 = hi ? segw<true>(td, 594 + i2, 694 + i2) : 0.f;
      float s0i = iscan(pa0, l);
      float tot0 = __shfl(s0i, 63);
      float s1i = iscan(hi ? pa1 : 0.f, l) + tot0;
      float S = __shfl(s1i, 35);
      float rc0 = S - s0i + pa0;
      float g0 = atop<true>(td, l, rc0);
      lam0 -= g0; dl2 += g0 * g0;
      if (hi) {
        float rc1 = S - s1i + pa1;
        float g1 = atop<true>(td, i2, rc1);
        lam1 -= g1; dl2 += g1 * g1;
      }
    }

#pragma unroll
    for (int o = 32; o > 0; o >>= 1) {
      r2  += __shfl_down(r2, o);
      ds2 += __shfl_down(ds2, o);
      dl2 += __shfl_down(dl2, o);
    }
    if (l == 0) { part[d][it][0] = r2; part[d][it][1] = ds2; part[d][it][2] = dl2; }
  }

  __syncthreads();
  {
    float* xout = out + (size_t)b * NVARS + d * 100;
    const float* xid = &pm[0][d * 100];
    xout[l] = xid[l];
    if (hi) xout[i2] = xid[i2];
  }
  if (tid < 20) {
    int it = tid;
    float R2 = 0.f, DS2 = 0.f, DL2 = 0.f;
    for (int dd = 0; dd < 7; ++dd) {
      R2 += part[dd][it][0]; DS2 += part[dd][it][1]; DL2 += part[dd][it][2];
    }
    float pr = sqrtf(R2), fp = sqrtf(DL2) + sqrtf(DS2);
    out[718848 + it * 1024 + b] = pr;
    out[739328 + it * 1024 + b] = fp;
    prfp[it] = pr; prfp[20 + it] = fp;
  }
  __syncthreads();
  if (tid == 0) {
    float ap = 0.f, af = 0.f;
    for (int it = 0; it < 20; ++it) { ap += prfp[it]; af += prfp[20 + it]; }
    out[716800 + b] = af / 20.f;
    out[717824 + b] = ap / 20.f;
  }
}

// =====================================================================
extern "C" void kernel_launch(void* const* d_in, const int* in_sizes, int n_in,
                              void* d_out, int out_size, void* d_ws, size_t ws_size,
                              hipStream_t stream) {
  (void)in_sizes; (void)n_in; (void)out_size;
  const float* input  = (const float*)d_in[0];
  const float* theta  = (const float*)d_in[1];
  const float* vstart = (const float*)d_in[2];
  const float* W1     = (const float*)d_in[3];
  const float* b1     = (const float*)d_in[4];
  const float* W2     = (const float*)d_in[5];
  const float* b2     = (const float*)d_in[6];
  float* out = (float*)d_out;

  double* wsd  = (double*)d_ws;
  double* zbuf = wsd;
  double* cid  = wsd + 12800;
  float* wsf  = (float*)d_ws;
  float* Qt   = wsf + 45600;
  float* med  = wsf + 55704;
  float* rinv = wsf + 56408;

  hipLaunchKernelGGL(qinv_kernel, dim3(1), dim3(128), 0, stream, zbuf, cid, Qt);
  hipLaunchKernelGGL(quantile_kernel, dim3(700), dim3(256), 0, stream, input, med, rinv);

  // ---- full (MFMA) path workspace layout, float-slot offsets ----
  const size_t HHI = 57112, HLO = 581400, W2TH = 1105688, W2TL = 4316952,
               OUT2 = 7528216, NEED = 13950744;
  const size_t ANH = OUT2, ANL = OUT2 + 360448, W1TH = OUT2 + 720896, W1TL = OUT2 + 1081344;

  if (ws_size >= NEED * 4ull) {
    ushort* an_h  = (ushort*)(wsf + ANH);
    ushort* an_l  = (ushort*)(wsf + ANL);
    ushort* w1t_h = (ushort*)(wsf + W1TH);
    ushort* w1t_l = (ushort*)(wsf + W1TL);
    ushort* h_h   = (ushort*)(wsf + HHI);
    ushort* h_l   = (ushort*)(wsf + HLO);
    ushort* w2t_h = (ushort*)(wsf + W2TH);
    ushort* w2t_l = (ushort*)(wsf + W2TL);
    float*  out2  = wsf + OUT2;

    hipLaunchKernelGGL(normalize_split, dim3((1024 * 704 + 255) / 256), dim3(256), 0, stream,
                       input, med, rinv, an_h, an_l);
    hipLaunchKernelGGL(tsplit, dim3(22, 32), dim3(32, 8), 0, stream,
                       W1, 700, 1024, 1024, 0, w1t_h, w1t_l, 704);
    hipLaunchKernelGGL(tsplit, dim3(32, 196), dim3(32, 8), 0, stream,
                       W2, 1024, 6958, 6958, 700, w2t_h, w2t_l, 1024);
    hipLaunchKernelGGL((gemm_mfma<1>), dim3(8, 8), dim3(256), 0, stream,
                       an_h, an_l, w1t_h, w1t_l, b1, 1024,
                       (float*)nullptr, h_h, h_l, 704, 1024);
    hipLaunchKernelGGL((gemm_mfma<0>), dim3(49, 8), dim3(256), 0, stream,
                       h_h, h_l, w2t_h, w2t_l, b2 + 700, 6258,
                       out2, (ushort*)nullptr, (ushort*)nullptr, 1024, 6272);
    hipLaunchKernelGGL(solver_kernel, dim3(1024), dim3(448), 0, stream,
                       out2, input, theta, vstart, Qt, out, 6272);
  } else {
    // ---- fallback (R2) path ----
    float* An   = wsf + 57112;
    float* h    = wsf + 773912;
    float* out2 = wsf + 1822488;
    if (ws_size < (size_t)(1822488 + 6408192) * 4) return;
    hipLaunchKernelGGL(normalize_kernel, dim3(2800), dim3(256), 0, stream, input, med, rinv, An);
    hipLaunchKernelGGL((gemm_kernel<true>), dim3(16, 16), dim3(256), 0, stream,
                       An, NVARS, W1, 1024, b1, h, 1024, 1024, NVARS);
    hipLaunchKernelGGL((gemm_kernel<false>), dim3(98, 16), dim3(256), 0, stream,
                       h, 1024, W2 + 700, 6958, b2 + 700, out2, 6258, 6258, 1024);
    hipLaunchKernelGGL(solver_kernel, dim3(1024), dim3(448), 0, stream,
                       out2, input, theta, vstart, Qt, out, 6258);
  }
}